// Round 3
// baseline (11025.149 us; speedup 1.0000x reference)
//
#include <hip/hip_runtime.h>
#include <cstdint>
#include <cstddef>

#define BIN_TILE    8192
#define BIN_THREADS 512
#define SP_THREADS  1024
#define SP_ROWS     256
#define SP_PITCH    129   // +1 word pad: bank = (r + c) & 31, breaks row-stride conflicts

static __device__ __forceinline__ unsigned f2bf_rne(float f) {
    unsigned u = __float_as_uint(f);
    return (u + 0x7FFFu + ((u >> 16) & 1u)) >> 16;
}
static __device__ __forceinline__ float bf2f(unsigned h) {
    return __uint_as_float(h << 16);
}

// ---------------- x0 = bf16(emb[node_ids]) ----------------
__global__ void gather_x0bf_k(const int* __restrict__ nid, const float* __restrict__ emb,
                              unsigned* __restrict__ xw, int N) {
    int i = blockIdx.x * blockDim.x + threadIdx.x;
    int n = i >> 6;
    if (n >= N) return;
    int l = i & 63;
    int s = nid[n];
    float2 v = *reinterpret_cast<const float2*>(emb + (size_t)s * 128 + 2 * l);
    xw[(size_t)n * 64 + l] = f2bf_rne(v.x) | (f2bf_rne(v.y) << 16);
}

// ---------------- global bucket histogram (LDS-staged merge) ----------------
__global__ void ghist_k(const int* __restrict__ erow, int* __restrict__ gcnt, int E, int nbkt) {
    extern __shared__ int lcnt[];
    for (int i = threadIdx.x; i < nbkt; i += blockDim.x) lcnt[i] = 0;
    __syncthreads();
    for (int e = blockIdx.x * blockDim.x + threadIdx.x; e < E; e += gridDim.x * blockDim.x)
        atomicAdd(&lcnt[erow[e] >> 8], 1);
    __syncthreads();
    for (int i = threadIdx.x; i < nbkt; i += blockDim.x)
        if (lcnt[i]) atomicAdd(&gcnt[i], lcnt[i]);
}

// ---------------- single-block exclusive scan over nbkt (<=1024) buckets ----------------
__global__ void scanB_k(const int* __restrict__ gcnt, int* __restrict__ fstart,
                        int* __restrict__ gcur, int nbkt) {
    __shared__ int ts[256];
    int tid = threadIdx.x;
    int idx = tid * 4;
    int v0 = (idx + 0 < nbkt) ? gcnt[idx + 0] : 0;
    int v1 = (idx + 1 < nbkt) ? gcnt[idx + 1] : 0;
    int v2 = (idx + 2 < nbkt) ? gcnt[idx + 2] : 0;
    int v3 = (idx + 3 < nbkt) ? gcnt[idx + 3] : 0;
    int local = v0 + v1 + v2 + v3;
    ts[tid] = local;
    __syncthreads();
    for (int off = 1; off < 256; off <<= 1) {
        int t = (tid >= off) ? ts[tid - off] : 0;
        __syncthreads();
        ts[tid] += t;
        __syncthreads();
    }
    int run = ts[tid] - local;
    if (idx + 0 < nbkt) { fstart[idx + 0] = run; gcur[idx + 0] = run; } run += v0;
    if (idx + 1 < nbkt) { fstart[idx + 1] = run; gcur[idx + 1] = run; } run += v1;
    if (idx + 2 < nbkt) { fstart[idx + 2] = run; gcur[idx + 2] = run; } run += v2;
    if (idx + 3 < nbkt) { fstart[idx + 3] = run; gcur[idx + 3] = run; }
    if (tid == 255) fstart[nbkt] = ts[255];
}

// ---------------- LDS-staged binning: tile -> bucket-grouped runs, coalesced flush ----------------
__global__ __launch_bounds__(BIN_THREADS) void bin_k(const int* __restrict__ erow,
                                                     const int* __restrict__ ecol,
                                                     const float* __restrict__ eval,
                                                     int* __restrict__ gcur,
                                                     uint2* __restrict__ cv, int E, int nbkt) {
    extern __shared__ char smem[];
    uint2*    stg  = (uint2*)smem;                          // BIN_TILE*8
    unsigned* gdst = (unsigned*)(smem + BIN_TILE * 8);      // BIN_TILE*4
    int* cnt   = (int*)(smem + BIN_TILE * 12);              // nbkt
    int* off   = cnt + nbkt;                                // nbkt
    int* gbase = off + nbkt;                                // nbkt
    int* cur   = gbase + nbkt;                              // nbkt
    __shared__ int ts[BIN_THREADS];

    int tid = threadIdx.x;
    int t0 = blockIdx.x * BIN_TILE;
    int tn = min(BIN_TILE, E - t0);

    for (int i = tid; i < nbkt; i += BIN_THREADS) cnt[i] = 0;
    __syncthreads();
    for (int i = tid; i < tn; i += BIN_THREADS)
        atomicAdd(&cnt[erow[t0 + i] >> 8], 1);
    __syncthreads();
    // exclusive scan of cnt -> off (2 items/thread, 1024 >= nbkt)
    {
        int idx = tid * 2;
        int a = (idx < nbkt) ? cnt[idx] : 0;
        int b = (idx + 1 < nbkt) ? cnt[idx + 1] : 0;
        int local = a + b;
        ts[tid] = local;
        __syncthreads();
        for (int o = 1; o < BIN_THREADS; o <<= 1) {
            int t = (tid >= o) ? ts[tid - o] : 0;
            __syncthreads();
            ts[tid] += t;
            __syncthreads();
        }
        int run = ts[tid] - local;
        if (idx < nbkt) off[idx] = run;
        if (idx + 1 < nbkt) off[idx + 1] = run + a;
    }
    __syncthreads();
    // reserve global runs (one atomic per non-empty bucket per block)
    for (int b = tid; b < nbkt; b += BIN_THREADS) {
        int c = cnt[b];
        gbase[b] = c ? atomicAdd(&gcur[b], c) : 0;
        cur[b] = 0;
    }
    __syncthreads();
    // scatter into bucket-grouped LDS staging
    for (int i = tid; i < tn; i += BIN_THREADS) {
        int r = erow[t0 + i];
        int b = r >> 8;
        unsigned meta = ((unsigned)(r & 255) << 18) | (unsigned)ecol[t0 + i];
        int s = off[b] + atomicAdd(&cur[b], 1);
        stg[s] = make_uint2(meta, __float_as_uint(eval[t0 + i]));
        gdst[s] = (unsigned)(gbase[b] + (s - off[b]));
    }
    __syncthreads();
    // flush: consecutive LDS slots -> consecutive global addresses within runs
    for (int s = tid; s < tn; s += BIN_THREADS)
        cv[gdst[s]] = stg[s];
}

// ---------------- SpMM: one block per 256-row bucket, LDS f32 accumulation ----------------
__global__ __launch_bounds__(SP_THREADS) void spmm_lds_k(const int* __restrict__ fstart,
                                                         const uint2* __restrict__ cv,
                                                         const unsigned* __restrict__ xw,
                                                         float* __restrict__ agg, int N) {
    extern __shared__ float a_lds[];   // SP_ROWS * SP_PITCH
    int tid = threadIdx.x;
    for (int i = tid; i < SP_ROWS * SP_PITCH; i += SP_THREADS) a_lds[i] = 0.f;
    __syncthreads();

    int fb = blockIdx.x;
    int fs = fstart[fb], fe = fstart[fb + 1];
    int total = fe - fs;
    int wid = tid >> 6, lane = tid & 63;
    int nw = SP_THREADS / 64;
    int per = (total + nw - 1) / nw;
    int ws = fs + wid * per;
    int we = min(ws + per, fe);
    int l2 = lane << 1;

    int e = ws;
    for (; e + 8 <= we; e += 8) {
        uint2 rr[8];
#pragma unroll
        for (int j = 0; j < 8; ++j) rr[j] = cv[e + j];
        unsigned mm[8], up[8];
        float vv[8];
#pragma unroll
        for (int j = 0; j < 8; ++j) {
            mm[j] = (unsigned)__builtin_amdgcn_readfirstlane((int)rr[j].x);
            vv[j] = __uint_as_float(__builtin_amdgcn_readfirstlane((int)rr[j].y));
            up[j] = xw[((size_t)(mm[j] & 0x3FFFFu) << 6) + lane];   // 4B/lane, 256B/edge
        }
#pragma unroll
        for (int j = 0; j < 8; ++j) {
            float p0 = vv[j] * bf2f(up[j] & 0xFFFFu);
            float p1 = vv[j] * bf2f(up[j] >> 16);
            int w0 = (int)(mm[j] >> 18) * SP_PITCH + l2;
            atomicAdd(&a_lds[w0], p0);
            atomicAdd(&a_lds[w0 + 1], p1);
        }
    }
    for (; e < we; ++e) {
        uint2 r = cv[e];
        unsigned m = (unsigned)__builtin_amdgcn_readfirstlane((int)r.x);
        float v = __uint_as_float(__builtin_amdgcn_readfirstlane((int)r.y));
        unsigned u = xw[((size_t)(m & 0x3FFFFu) << 6) + lane];
        int w0 = (int)(m >> 18) * SP_PITCH + l2;
        atomicAdd(&a_lds[w0], v * bf2f(u & 0xFFFFu));
        atomicAdd(&a_lds[w0 + 1], v * bf2f(u >> 16));
    }
    __syncthreads();
    // writeback: 8192 float4s, coalesced
    int base = fb << 8;
#pragma unroll
    for (int k = 0; k < 8; ++k) {
        int q = tid + k * SP_THREADS;
        int r = q >> 5;
        int c4 = (q & 31) << 2;
        if (base + r < N) {
            float4 o;
            int w = r * SP_PITCH + c4;
            o.x = a_lds[w]; o.y = a_lds[w + 1]; o.z = a_lds[w + 2]; o.w = a_lds[w + 3];
            *reinterpret_cast<float4*>(agg + (size_t)(base + r) * 128 + c4) = o;
        }
    }
}

// ---------------- dense: out = relu(agg @ W + b); f32 or bf16 output ----------------
#define DB_ROWS 8
__global__ __launch_bounds__(256) void dense_k(const float* __restrict__ agg,
                                               const float* __restrict__ W,
                                               const float* __restrict__ b,
                                               float* __restrict__ out_f,
                                               unsigned short* __restrict__ out_bf, int N) {
    __shared__ float arow[DB_ROWS][128];
    __shared__ float partial[DB_ROWS][128];
    int tid = threadIdx.x;
    int j = tid & 127;
    int half = tid >> 7;
    float w[64];
#pragma unroll
    for (int i = 0; i < 64; ++i) w[i] = W[(size_t)(half * 64 + i) * 128 + j];
    float bj = b[j];

    for (int base = blockIdx.x * DB_ROWS; base < N; base += gridDim.x * DB_ROWS) {
        for (int idx = tid; idx < DB_ROWS * 128; idx += 256) {
            int rr = base + (idx >> 7);
            arow[idx >> 7][idx & 127] = (rr < N) ? agg[(size_t)rr * 128 + (idx & 127)] : 0.f;
        }
        __syncthreads();
        float acc[DB_ROWS];
#pragma unroll
        for (int r = 0; r < DB_ROWS; ++r) {
            float s = 0.f;
#pragma unroll
            for (int i = 0; i < 64; ++i) s = fmaf(arow[r][half * 64 + i], w[i], s);
            acc[r] = s;
        }
        __syncthreads();
        if (half == 1) {
#pragma unroll
            for (int r = 0; r < DB_ROWS; ++r) partial[r][j] = acc[r];
        }
        __syncthreads();
        if (half == 0) {
#pragma unroll
            for (int r = 0; r < DB_ROWS; ++r) {
                if (base + r < N) {
                    float v = fmaxf(acc[r] + partial[r][j] + bj, 0.f);
                    if (out_bf) out_bf[(size_t)(base + r) * 128 + j] = (unsigned short)f2bf_rne(v);
                    else        out_f [(size_t)(base + r) * 128 + j] = v;
                }
            }
        }
        __syncthreads();
    }
}

extern "C" void kernel_launch(void* const* d_in, const int* in_sizes, int n_in,
                              void* d_out, int out_size, void* d_ws, size_t ws_size,
                              hipStream_t stream) {
    const int*   nid  = (const int*)d_in[0];
    const int*   erow = (const int*)d_in[1];
    const int*   ecol = (const int*)d_in[2];
    const float* eval = (const float*)d_in[3];
    const float* emb  = (const float*)d_in[4];
    const float* W1   = (const float*)d_in[5];
    const float* b1   = (const float*)d_in[6];
    const float* W2   = (const float*)d_in[7];
    const float* b2   = (const float*)d_in[8];
    int N = in_sizes[0];
    int E = in_sizes[1];
    float* out = (float*)d_out;

    int NBKT = (N + 255) >> 8;                    // 782 buckets of 256 rows

    auto al = [](size_t x) { return (x + 255) & ~(size_t)255; };
    char* w = (char*)d_ws;
    int*      gcnt   = (int*)w;      w += al((size_t)NBKT * 4);
    int*      fstart = (int*)w;      w += al((size_t)(NBKT + 1) * 4);
    int*      gcur   = (int*)w;      w += al((size_t)NBKT * 4);
    uint2*    cv     = (uint2*)w;    w += al((size_t)E * 8);
    unsigned* xw     = (unsigned*)w; w += al((size_t)N * 64 * 4);   // bf16 x, 2 per u32

    float* agg = out;   // d_out doubles as agg scratch (dead until final dense)

    hipMemsetAsync(gcnt, 0, (size_t)NBKT * 4, stream);

    // x0 (bf16)
    gather_x0bf_k<<<(N * 64 + 255) / 256, 256, 0, stream>>>(nid, emb, xw, N);

    // bucket-grouped edge records
    size_t ghistLds = (size_t)NBKT * 4;
    ghist_k<<<1024, 256, ghistLds, stream>>>(erow, gcnt, E, NBKT);
    scanB_k<<<1, 256, 0, stream>>>(gcnt, fstart, gcur, NBKT);
    size_t binLds = (size_t)BIN_TILE * 12 + (size_t)NBKT * 4 * 4;
    int binBlocks = (E + BIN_TILE - 1) / BIN_TILE;
    bin_k<<<binBlocks, BIN_THREADS, binLds, stream>>>(erow, ecol, eval, gcur, cv, E, NBKT);

    size_t spLds = (size_t)SP_ROWS * SP_PITCH * 4;

    // layer 1: agg = A @ x0 ; x1(bf16) = relu(agg@W1+b1)
    spmm_lds_k<<<NBKT, SP_THREADS, spLds, stream>>>(fstart, cv, xw, agg, N);
    dense_k<<<2048, 256, 0, stream>>>(agg, W1, b1, nullptr, (unsigned short*)xw, N);

    // layer 2: agg = A @ x1 ; out(f32) = relu(agg@W2+b2)
    spmm_lds_k<<<NBKT, SP_THREADS, spLds, stream>>>(fstart, cv, xw, agg, N);
    dense_k<<<2048, 256, 0, stream>>>(agg, W2, b2, out, nullptr, N);
}

// Round 5
// 958.502 us; speedup vs baseline: 11.5025x; 11.5025x over previous
//
#include <hip/hip_runtime.h>
#include <cstdint>
#include <cstddef>

#define BIN_TILE    8192
#define BIN_THREADS 512

static __device__ __forceinline__ unsigned f2bf_rne(float f) {
    unsigned u = __float_as_uint(f);
    return (u + 0x7FFFu + ((u >> 16) & 1u)) >> 16;
}
static __device__ __forceinline__ float bf2f(unsigned h) {
    return __uint_as_float(h << 16);
}

// ---------------- x0 = bf16(emb[node_ids]) ----------------
__global__ void gather_x0bf_k(const int* __restrict__ nid, const float* __restrict__ emb,
                              unsigned* __restrict__ xw, int N) {
    int i = blockIdx.x * blockDim.x + threadIdx.x;
    int n = i >> 6;
    if (n >= N) return;
    int l = i & 63;
    int s = nid[n];
    float2 v = *reinterpret_cast<const float2*>(emb + (size_t)s * 128 + 2 * l);
    xw[(size_t)n * 64 + l] = f2bf_rne(v.x) | (f2bf_rne(v.y) << 16);
}

// ---------------- global bucket histogram (LDS-staged merge) ----------------
__global__ void ghist_k(const int* __restrict__ erow, int* __restrict__ gcnt, int E, int nbkt) {
    extern __shared__ int lcnt[];
    for (int i = threadIdx.x; i < nbkt; i += blockDim.x) lcnt[i] = 0;
    __syncthreads();
    for (int e = blockIdx.x * blockDim.x + threadIdx.x; e < E; e += gridDim.x * blockDim.x)
        atomicAdd(&lcnt[erow[e] >> 8], 1);
    __syncthreads();
    for (int i = threadIdx.x; i < nbkt; i += blockDim.x)
        if (lcnt[i]) atomicAdd(&gcnt[i], lcnt[i]);
}

// ---------------- single-block exclusive scan over nbkt (<=1024) buckets ----------------
__global__ void scanB_k(const int* __restrict__ gcnt, int* __restrict__ fstart,
                        int* __restrict__ gcur, int nbkt) {
    __shared__ int ts[256];
    int tid = threadIdx.x;
    int idx = tid * 4;
    int v0 = (idx + 0 < nbkt) ? gcnt[idx + 0] : 0;
    int v1 = (idx + 1 < nbkt) ? gcnt[idx + 1] : 0;
    int v2 = (idx + 2 < nbkt) ? gcnt[idx + 2] : 0;
    int v3 = (idx + 3 < nbkt) ? gcnt[idx + 3] : 0;
    int local = v0 + v1 + v2 + v3;
    ts[tid] = local;
    __syncthreads();
    for (int off = 1; off < 256; off <<= 1) {
        int t = (tid >= off) ? ts[tid - off] : 0;
        __syncthreads();
        ts[tid] += t;
        __syncthreads();
    }
    int run = ts[tid] - local;
    if (idx + 0 < nbkt) { fstart[idx + 0] = run; gcur[idx + 0] = run; } run += v0;
    if (idx + 1 < nbkt) { fstart[idx + 1] = run; gcur[idx + 1] = run; } run += v1;
    if (idx + 2 < nbkt) { fstart[idx + 2] = run; gcur[idx + 2] = run; } run += v2;
    if (idx + 3 < nbkt) { fstart[idx + 3] = run; gcur[idx + 3] = run; }
    if (tid == 255) fstart[nbkt] = ts[255];
}

// ---------------- LDS-staged binning: tile -> bucket-grouped runs, coalesced flush ----------------
__global__ __launch_bounds__(BIN_THREADS) void bin_k(const int* __restrict__ erow,
                                                     const int* __restrict__ ecol,
                                                     const float* __restrict__ eval,
                                                     int* __restrict__ gcur,
                                                     uint2* __restrict__ cv1, int E, int nbkt) {
    extern __shared__ char smem[];
    uint2*    stg  = (uint2*)smem;                          // BIN_TILE*8
    unsigned* gdst = (unsigned*)(smem + BIN_TILE * 8);      // BIN_TILE*4
    int* cnt   = (int*)(smem + BIN_TILE * 12);              // nbkt
    int* off   = cnt + nbkt;                                // nbkt
    int* gbase = off + nbkt;                                // nbkt
    int* cur   = gbase + nbkt;                              // nbkt
    __shared__ int ts[BIN_THREADS];

    int tid = threadIdx.x;
    int t0 = blockIdx.x * BIN_TILE;
    int tn = min(BIN_TILE, E - t0);

    for (int i = tid; i < nbkt; i += BIN_THREADS) cnt[i] = 0;
    __syncthreads();
    for (int i = tid; i < tn; i += BIN_THREADS)
        atomicAdd(&cnt[erow[t0 + i] >> 8], 1);
    __syncthreads();
    {   // exclusive scan of cnt -> off (2 items/thread)
        int idx = tid * 2;
        int a = (idx < nbkt) ? cnt[idx] : 0;
        int b = (idx + 1 < nbkt) ? cnt[idx + 1] : 0;
        int local = a + b;
        ts[tid] = local;
        __syncthreads();
        for (int o = 1; o < BIN_THREADS; o <<= 1) {
            int t = (tid >= o) ? ts[tid - o] : 0;
            __syncthreads();
            ts[tid] += t;
            __syncthreads();
        }
        int run = ts[tid] - local;
        if (idx < nbkt) off[idx] = run;
        if (idx + 1 < nbkt) off[idx + 1] = run + a;
    }
    __syncthreads();
    for (int b = tid; b < nbkt; b += BIN_THREADS) {
        int c = cnt[b];
        gbase[b] = c ? atomicAdd(&gcur[b], c) : 0;
        cur[b] = 0;
    }
    __syncthreads();
    for (int i = tid; i < tn; i += BIN_THREADS) {
        int r = erow[t0 + i];
        int b = r >> 8;
        unsigned meta = ((unsigned)(r & 255) << 18) | (unsigned)ecol[t0 + i];
        int s = off[b] + atomicAdd(&cur[b], 1);
        stg[s] = make_uint2(meta, __float_as_uint(eval[t0 + i]));
        gdst[s] = (unsigned)(gbase[b] + (s - off[b]));
    }
    __syncthreads();
    for (int s = tid; s < tn; s += BIN_THREADS)
        cv1[gdst[s]] = stg[s];
}

// ---------------- per-bucket row sort: bucket-grouped -> row-sorted, plus rs[] ----------------
__global__ __launch_bounds__(256) void rowsort_k(const int* __restrict__ fstart,
                                                 const uint2* __restrict__ cv1,
                                                 uint2* __restrict__ cv2,
                                                 int* __restrict__ rs, int N, int E) {
    __shared__ int cnt[256];
    __shared__ int cur[256];
    __shared__ int ts[256];
    int fb = blockIdx.x;
    int base = fb << 8;
    int tid = threadIdx.x;
    cnt[tid] = 0;
    __syncthreads();
    int fs = fstart[fb], fe = fstart[fb + 1];
    for (int i = fs + tid; i < fe; i += 256)
        atomicAdd(&cnt[cv1[i].x >> 18], 1);
    __syncthreads();
    int v = cnt[tid];
    ts[tid] = v;
    __syncthreads();
    for (int off = 1; off < 256; off <<= 1) {
        int t = (tid >= off) ? ts[tid - off] : 0;
        __syncthreads();
        ts[tid] += t;
        __syncthreads();
    }
    int start = fs + ts[tid] - v;   // this row's global start
    int row = base + tid;
    if (row < N) rs[row] = start;
    cur[tid] = start;
    if (fb == 0 && tid == 0) rs[N] = E;
    __syncthreads();
    for (int i = fs + tid; i < fe; i += 256) {
        uint2 t2 = cv1[i];
        int pos = atomicAdd(&cur[t2.x >> 18], 1);
        cv2[pos] = make_uint2(t2.x & 0x3FFFFu, t2.y);
    }
}

// ---------------- SpMM: wave = row, register accumulation, uniform loop, no shfl ----------------
__global__ void spmm_k(const int* __restrict__ rs, const uint2* __restrict__ cv,
                       const unsigned* __restrict__ xw, float* __restrict__ agg, int N) {
    int gw = (blockIdx.x * blockDim.x + threadIdx.x) >> 6;
    if (gw >= N) return;
    int lane = threadIdx.x & 63;
    int s = __builtin_amdgcn_readfirstlane(rs[gw]);
    int e = __builtin_amdgcn_readfirstlane(rs[gw + 1]);
    float a0 = 0.f, a1 = 0.f;
    int k = s;
    for (; k + 3 < e; k += 4) {                 // 4 independent gathers in flight
        uint2 p0 = cv[k];
        uint2 p1 = cv[k + 1];
        uint2 p2 = cv[k + 2];
        uint2 p3 = cv[k + 3];
        unsigned u0 = xw[((size_t)p0.x << 6) + lane];
        unsigned u1 = xw[((size_t)p1.x << 6) + lane];
        unsigned u2 = xw[((size_t)p2.x << 6) + lane];
        unsigned u3 = xw[((size_t)p3.x << 6) + lane];
        float v0 = __uint_as_float(p0.y);
        float v1 = __uint_as_float(p1.y);
        float v2 = __uint_as_float(p2.y);
        float v3 = __uint_as_float(p3.y);
        a0 = fmaf(v0, bf2f(u0 & 0xFFFFu), a0); a1 = fmaf(v0, bf2f(u0 >> 16), a1);
        a0 = fmaf(v1, bf2f(u1 & 0xFFFFu), a0); a1 = fmaf(v1, bf2f(u1 >> 16), a1);
        a0 = fmaf(v2, bf2f(u2 & 0xFFFFu), a0); a1 = fmaf(v2, bf2f(u2 >> 16), a1);
        a0 = fmaf(v3, bf2f(u3 & 0xFFFFu), a0); a1 = fmaf(v3, bf2f(u3 >> 16), a1);
    }
    for (; k < e; ++k) {
        uint2 p0 = cv[k];
        unsigned u0 = xw[((size_t)p0.x << 6) + lane];
        float v0 = __uint_as_float(p0.y);
        a0 = fmaf(v0, bf2f(u0 & 0xFFFFu), a0);
        a1 = fmaf(v0, bf2f(u0 >> 16), a1);
    }
    float2 o; o.x = a0; o.y = a1;
    *reinterpret_cast<float2*>(agg + (size_t)gw * 128 + (lane << 1)) = o;
}

// ---------------- dense: out = relu(agg @ W + b); f32 or bf16 output ----------------
#define DB_ROWS 8
__global__ __launch_bounds__(256) void dense_k(const float* __restrict__ agg,
                                               const float* __restrict__ W,
                                               const float* __restrict__ b,
                                               float* __restrict__ out_f,
                                               unsigned short* __restrict__ out_bf, int N) {
    __shared__ float arow[DB_ROWS][128];
    __shared__ float partial[DB_ROWS][128];
    int tid = threadIdx.x;
    int j = tid & 127;
    int half = tid >> 7;
    float w[64];
#pragma unroll
    for (int i = 0; i < 64; ++i) w[i] = W[(size_t)(half * 64 + i) * 128 + j];
    float bj = b[j];

    for (int base = blockIdx.x * DB_ROWS; base < N; base += gridDim.x * DB_ROWS) {
        for (int idx = tid; idx < DB_ROWS * 128; idx += 256) {
            int rr = base + (idx >> 7);
            arow[idx >> 7][idx & 127] = (rr < N) ? agg[(size_t)rr * 128 + (idx & 127)] : 0.f;
        }
        __syncthreads();
        float acc[DB_ROWS];
#pragma unroll
        for (int r = 0; r < DB_ROWS; ++r) {
            float s = 0.f;
#pragma unroll
            for (int i = 0; i < 64; ++i) s = fmaf(arow[r][half * 64 + i], w[i], s);
            acc[r] = s;
        }
        __syncthreads();
        if (half == 1) {
#pragma unroll
            for (int r = 0; r < DB_ROWS; ++r) partial[r][j] = acc[r];
        }
        __syncthreads();
        if (half == 0) {
#pragma unroll
            for (int r = 0; r < DB_ROWS; ++r) {
                if (base + r < N) {
                    float v = fmaxf(acc[r] + partial[r][j] + bj, 0.f);
                    if (out_bf) out_bf[(size_t)(base + r) * 128 + j] = (unsigned short)f2bf_rne(v);
                    else        out_f [(size_t)(base + r) * 128 + j] = v;
                }
            }
        }
        __syncthreads();
    }
}

extern "C" void kernel_launch(void* const* d_in, const int* in_sizes, int n_in,
                              void* d_out, int out_size, void* d_ws, size_t ws_size,
                              hipStream_t stream) {
    const int*   nid  = (const int*)d_in[0];
    const int*   erow = (const int*)d_in[1];
    const int*   ecol = (const int*)d_in[2];
    const float* eval = (const float*)d_in[3];
    const float* emb  = (const float*)d_in[4];
    const float* W1   = (const float*)d_in[5];
    const float* b1   = (const float*)d_in[6];
    const float* W2   = (const float*)d_in[7];
    const float* b2   = (const float*)d_in[8];
    int N = in_sizes[0];
    int E = in_sizes[1];
    float* out = (float*)d_out;

    int NBKT = (N + 255) >> 8;                    // buckets of 256 rows

    auto al = [](size_t x) { return (x + 255) & ~(size_t)255; };
    char* w = (char*)d_ws;
    int*      gcnt   = (int*)w;      w += al((size_t)NBKT * 4);
    int*      fstart = (int*)w;      w += al((size_t)(NBKT + 1) * 4);
    int*      gcur   = (int*)w;      w += al((size_t)NBKT * 4);
    int*      rs     = (int*)w;      w += al((size_t)(N + 1) * 4);
    uint2*    cv1    = (uint2*)w;    w += al((size_t)E * 8);
    uint2*    cv2    = (uint2*)w;    w += al((size_t)E * 8);
    unsigned* xw     = (unsigned*)w; w += al((size_t)N * 64 * 4);   // bf16 x

    float* agg = out;   // d_out doubles as agg scratch (dead until final dense)

    hipMemsetAsync(gcnt, 0, (size_t)NBKT * 4, stream);

    // x0 (bf16)
    gather_x0bf_k<<<(N * 64 + 255) / 256, 256, 0, stream>>>(nid, emb, xw, N);

    // CSR build: bucket-group then per-bucket row sort
    size_t ghistLds = (size_t)NBKT * 4;
    ghist_k<<<1024, 256, ghistLds, stream>>>(erow, gcnt, E, NBKT);
    scanB_k<<<1, 256, 0, stream>>>(gcnt, fstart, gcur, NBKT);
    size_t binLds = (size_t)BIN_TILE * 12 + (size_t)NBKT * 4 * 4;
    int binBlocks = (E + BIN_TILE - 1) / BIN_TILE;
    bin_k<<<binBlocks, BIN_THREADS, binLds, stream>>>(erow, ecol, eval, gcur, cv1, E, NBKT);
    rowsort_k<<<NBKT, 256, 0, stream>>>(fstart, cv1, cv2, rs, N, E);

    // layer 1: agg = A @ x0 ; x1(bf16) = relu(agg@W1+b1)
    spmm_k<<<(N * 64 + 255) / 256, 256, 0, stream>>>(rs, cv2, xw, agg, N);
    dense_k<<<2048, 256, 0, stream>>>(agg, W1, b1, nullptr, (unsigned short*)xw, N);

    // layer 2: agg = A @ x1 ; out(f32) = relu(agg@W2+b2)
    spmm_k<<<(N * 64 + 255) / 256, 256, 0, stream>>>(rs, cv2, xw, agg, N);
    dense_k<<<2048, 256, 0, stream>>>(agg, W2, b2, out, nullptr, N);
}

// Round 6
// 940.042 us; speedup vs baseline: 11.7284x; 1.0196x over previous
//
#include <hip/hip_runtime.h>
#include <cstdint>
#include <cstddef>

#define BIN_TILE    4096
#define BIN_THREADS 512

static __device__ __forceinline__ unsigned f2bf_rne(float f) {
    unsigned u = __float_as_uint(f);
    return (u + 0x7FFFu + ((u >> 16) & 1u)) >> 16;
}
static __device__ __forceinline__ float bf2f(unsigned h) {
    return __uint_as_float(h << 16);
}

// ---------------- x0 = bf16(emb[node_ids]) ----------------
__global__ void gather_x0bf_k(const int* __restrict__ nid, const float* __restrict__ emb,
                              unsigned* __restrict__ xw, int N) {
    int i = blockIdx.x * blockDim.x + threadIdx.x;
    int n = i >> 6;
    if (n >= N) return;
    int l = i & 63;
    int s = nid[n];
    float2 v = *reinterpret_cast<const float2*>(emb + (size_t)s * 128 + 2 * l);
    xw[(size_t)n * 64 + l] = f2bf_rne(v.x) | (f2bf_rne(v.y) << 16);
}

// ---------------- global bucket histogram (LDS-staged merge) ----------------
__global__ void ghist_k(const int* __restrict__ erow, int* __restrict__ gcnt, int E, int nbkt) {
    extern __shared__ int lcnt[];
    for (int i = threadIdx.x; i < nbkt; i += blockDim.x) lcnt[i] = 0;
    __syncthreads();
    for (int e = blockIdx.x * blockDim.x + threadIdx.x; e < E; e += gridDim.x * blockDim.x)
        atomicAdd(&lcnt[erow[e] >> 8], 1);
    __syncthreads();
    for (int i = threadIdx.x; i < nbkt; i += blockDim.x)
        if (lcnt[i]) atomicAdd(&gcnt[i], lcnt[i]);
}

// ---------------- single-block exclusive scan over nbkt (<=1024) buckets ----------------
__global__ void scanB_k(const int* __restrict__ gcnt, int* __restrict__ fstart,
                        int* __restrict__ gcur, int nbkt) {
    __shared__ int ts[256];
    int tid = threadIdx.x;
    int idx = tid * 4;
    int v0 = (idx + 0 < nbkt) ? gcnt[idx + 0] : 0;
    int v1 = (idx + 1 < nbkt) ? gcnt[idx + 1] : 0;
    int v2 = (idx + 2 < nbkt) ? gcnt[idx + 2] : 0;
    int v3 = (idx + 3 < nbkt) ? gcnt[idx + 3] : 0;
    int local = v0 + v1 + v2 + v3;
    ts[tid] = local;
    __syncthreads();
    for (int off = 1; off < 256; off <<= 1) {
        int t = (tid >= off) ? ts[tid - off] : 0;
        __syncthreads();
        ts[tid] += t;
        __syncthreads();
    }
    int run = ts[tid] - local;
    if (idx + 0 < nbkt) { fstart[idx + 0] = run; gcur[idx + 0] = run; } run += v0;
    if (idx + 1 < nbkt) { fstart[idx + 1] = run; gcur[idx + 1] = run; } run += v1;
    if (idx + 2 < nbkt) { fstart[idx + 2] = run; gcur[idx + 2] = run; } run += v2;
    if (idx + 3 < nbkt) { fstart[idx + 3] = run; gcur[idx + 3] = run; }
    if (tid == 255) fstart[nbkt] = ts[255];
}

// ---------------- LDS-staged binning: tile -> bucket-grouped runs, coalesced flush ----------------
__global__ __launch_bounds__(BIN_THREADS) void bin_k(const int* __restrict__ erow,
                                                     const int* __restrict__ ecol,
                                                     const float* __restrict__ eval,
                                                     int* __restrict__ gcur,
                                                     uint2* __restrict__ cv1, int E, int nbkt) {
    extern __shared__ char smem[];
    uint2*    stg  = (uint2*)smem;                          // BIN_TILE*8
    unsigned* gdst = (unsigned*)(smem + BIN_TILE * 8);      // BIN_TILE*4
    int* cnt   = (int*)(smem + BIN_TILE * 12);              // nbkt
    int* off   = cnt + nbkt;                                // nbkt
    int* gbase = off + nbkt;                                // nbkt
    int* cur   = gbase + nbkt;                              // nbkt
    __shared__ int ts[BIN_THREADS];

    int tid = threadIdx.x;
    int t0 = blockIdx.x * BIN_TILE;
    int tn = min(BIN_TILE, E - t0);

    for (int i = tid; i < nbkt; i += BIN_THREADS) cnt[i] = 0;
    __syncthreads();
    for (int i = tid; i < tn; i += BIN_THREADS)
        atomicAdd(&cnt[erow[t0 + i] >> 8], 1);
    __syncthreads();
    {   // exclusive scan of cnt -> off (2 items/thread)
        int idx = tid * 2;
        int a = (idx < nbkt) ? cnt[idx] : 0;
        int b = (idx + 1 < nbkt) ? cnt[idx + 1] : 0;
        int local = a + b;
        ts[tid] = local;
        __syncthreads();
        for (int o = 1; o < BIN_THREADS; o <<= 1) {
            int t = (tid >= o) ? ts[tid - o] : 0;
            __syncthreads();
            ts[tid] += t;
            __syncthreads();
        }
        int run = ts[tid] - local;
        if (idx < nbkt) off[idx] = run;
        if (idx + 1 < nbkt) off[idx + 1] = run + a;
    }
    __syncthreads();
    for (int b = tid; b < nbkt; b += BIN_THREADS) {
        int c = cnt[b];
        gbase[b] = c ? atomicAdd(&gcur[b], c) : 0;
        cur[b] = 0;
    }
    __syncthreads();
    for (int i = tid; i < tn; i += BIN_THREADS) {
        int r = erow[t0 + i];
        int b = r >> 8;
        unsigned meta = ((unsigned)(r & 255) << 18) | (unsigned)ecol[t0 + i];
        int s = off[b] + atomicAdd(&cur[b], 1);
        stg[s] = make_uint2(meta, __float_as_uint(eval[t0 + i]));
        gdst[s] = (unsigned)(gbase[b] + (s - off[b]));
    }
    __syncthreads();
    for (int s = tid; s < tn; s += BIN_THREADS)
        cv1[gdst[s]] = stg[s];
}

// ---------------- per-bucket row sort: bucket-grouped -> row-sorted, plus rs[] ----------------
__global__ __launch_bounds__(256) void rowsort_k(const int* __restrict__ fstart,
                                                 const uint2* __restrict__ cv1,
                                                 uint2* __restrict__ cv2,
                                                 int* __restrict__ rs, int N, int E) {
    __shared__ int cnt[256];
    __shared__ int cur[256];
    __shared__ int ts[256];
    int fb = blockIdx.x;
    int base = fb << 8;
    int tid = threadIdx.x;
    cnt[tid] = 0;
    __syncthreads();
    int fs = fstart[fb], fe = fstart[fb + 1];
    for (int i = fs + tid; i < fe; i += 256)
        atomicAdd(&cnt[cv1[i].x >> 18], 1);
    __syncthreads();
    int v = cnt[tid];
    ts[tid] = v;
    __syncthreads();
    for (int off = 1; off < 256; off <<= 1) {
        int t = (tid >= off) ? ts[tid - off] : 0;
        __syncthreads();
        ts[tid] += t;
        __syncthreads();
    }
    int start = fs + ts[tid] - v;   // this row's global start
    int row = base + tid;
    if (row < N) rs[row] = start;
    cur[tid] = start;
    if (fb == 0 && tid == 0) rs[N] = E;
    __syncthreads();
    for (int i = fs + tid; i < fe; i += 256) {
        uint2 t2 = cv1[i];
        int pos = atomicAdd(&cur[t2.x >> 18], 1);
        cv2[pos] = make_uint2(t2.x & 0x3FFFFu, t2.y);
    }
}

// ---------------- SpMM: wave = row, register accumulation, 8 gathers in flight ----------------
__global__ void spmm_k(const int* __restrict__ rs, const uint2* __restrict__ cv,
                       const unsigned* __restrict__ xw, float* __restrict__ agg, int N) {
    int gw = (blockIdx.x * blockDim.x + threadIdx.x) >> 6;
    if (gw >= N) return;
    int lane = threadIdx.x & 63;
    int s = __builtin_amdgcn_readfirstlane(rs[gw]);
    int e = __builtin_amdgcn_readfirstlane(rs[gw + 1]);
    float a0 = 0.f, a1 = 0.f;
    int k = s;
    for (; k + 7 < e; k += 8) {                 // 8 independent gathers in flight
        uint2 p0 = cv[k];
        uint2 p1 = cv[k + 1];
        uint2 p2 = cv[k + 2];
        uint2 p3 = cv[k + 3];
        uint2 p4 = cv[k + 4];
        uint2 p5 = cv[k + 5];
        uint2 p6 = cv[k + 6];
        uint2 p7 = cv[k + 7];
        unsigned u0 = xw[((size_t)p0.x << 6) + lane];
        unsigned u1 = xw[((size_t)p1.x << 6) + lane];
        unsigned u2 = xw[((size_t)p2.x << 6) + lane];
        unsigned u3 = xw[((size_t)p3.x << 6) + lane];
        unsigned u4 = xw[((size_t)p4.x << 6) + lane];
        unsigned u5 = xw[((size_t)p5.x << 6) + lane];
        unsigned u6 = xw[((size_t)p6.x << 6) + lane];
        unsigned u7 = xw[((size_t)p7.x << 6) + lane];
        float v0 = __uint_as_float(p0.y);
        float v1 = __uint_as_float(p1.y);
        float v2 = __uint_as_float(p2.y);
        float v3 = __uint_as_float(p3.y);
        float v4 = __uint_as_float(p4.y);
        float v5 = __uint_as_float(p5.y);
        float v6 = __uint_as_float(p6.y);
        float v7 = __uint_as_float(p7.y);
        a0 = fmaf(v0, bf2f(u0 & 0xFFFFu), a0); a1 = fmaf(v0, bf2f(u0 >> 16), a1);
        a0 = fmaf(v1, bf2f(u1 & 0xFFFFu), a0); a1 = fmaf(v1, bf2f(u1 >> 16), a1);
        a0 = fmaf(v2, bf2f(u2 & 0xFFFFu), a0); a1 = fmaf(v2, bf2f(u2 >> 16), a1);
        a0 = fmaf(v3, bf2f(u3 & 0xFFFFu), a0); a1 = fmaf(v3, bf2f(u3 >> 16), a1);
        a0 = fmaf(v4, bf2f(u4 & 0xFFFFu), a0); a1 = fmaf(v4, bf2f(u4 >> 16), a1);
        a0 = fmaf(v5, bf2f(u5 & 0xFFFFu), a0); a1 = fmaf(v5, bf2f(u5 >> 16), a1);
        a0 = fmaf(v6, bf2f(u6 & 0xFFFFu), a0); a1 = fmaf(v6, bf2f(u6 >> 16), a1);
        a0 = fmaf(v7, bf2f(u7 & 0xFFFFu), a0); a1 = fmaf(v7, bf2f(u7 >> 16), a1);
    }
    for (; k < e; ++k) {
        uint2 p0 = cv[k];
        unsigned u0 = xw[((size_t)p0.x << 6) + lane];
        float v0 = __uint_as_float(p0.y);
        a0 = fmaf(v0, bf2f(u0 & 0xFFFFu), a0);
        a1 = fmaf(v0, bf2f(u0 >> 16), a1);
    }
    float2 o; o.x = a0; o.y = a1;
    *reinterpret_cast<float2*>(agg + (size_t)gw * 128 + (lane << 1)) = o;
}

// ---------------- dense: out = relu(agg @ W + b); f32 or bf16 output ----------------
#define DB_ROWS 8
__global__ __launch_bounds__(256) void dense_k(const float* __restrict__ agg,
                                               const float* __restrict__ W,
                                               const float* __restrict__ b,
                                               float* __restrict__ out_f,
                                               unsigned short* __restrict__ out_bf, int N) {
    __shared__ float arow[DB_ROWS][128];
    __shared__ float partial[DB_ROWS][128];
    int tid = threadIdx.x;
    int j = tid & 127;
    int half = tid >> 7;
    float w[64];
#pragma unroll
    for (int i = 0; i < 64; ++i) w[i] = W[(size_t)(half * 64 + i) * 128 + j];
    float bj = b[j];

    for (int base = blockIdx.x * DB_ROWS; base < N; base += gridDim.x * DB_ROWS) {
        for (int idx = tid; idx < DB_ROWS * 128; idx += 256) {
            int rr = base + (idx >> 7);
            arow[idx >> 7][idx & 127] = (rr < N) ? agg[(size_t)rr * 128 + (idx & 127)] : 0.f;
        }
        __syncthreads();
        float acc[DB_ROWS];
#pragma unroll
        for (int r = 0; r < DB_ROWS; ++r) {
            float s = 0.f;
#pragma unroll
            for (int i = 0; i < 64; ++i) s = fmaf(arow[r][half * 64 + i], w[i], s);
            acc[r] = s;
        }
        __syncthreads();
        if (half == 1) {
#pragma unroll
            for (int r = 0; r < DB_ROWS; ++r) partial[r][j] = acc[r];
        }
        __syncthreads();
        if (half == 0) {
#pragma unroll
            for (int r = 0; r < DB_ROWS; ++r) {
                if (base + r < N) {
                    float v = fmaxf(acc[r] + partial[r][j] + bj, 0.f);
                    if (out_bf) out_bf[(size_t)(base + r) * 128 + j] = (unsigned short)f2bf_rne(v);
                    else        out_f [(size_t)(base + r) * 128 + j] = v;
                }
            }
        }
        __syncthreads();
    }
}

extern "C" void kernel_launch(void* const* d_in, const int* in_sizes, int n_in,
                              void* d_out, int out_size, void* d_ws, size_t ws_size,
                              hipStream_t stream) {
    const int*   nid  = (const int*)d_in[0];
    const int*   erow = (const int*)d_in[1];
    const int*   ecol = (const int*)d_in[2];
    const float* eval = (const float*)d_in[3];
    const float* emb  = (const float*)d_in[4];
    const float* W1   = (const float*)d_in[5];
    const float* b1   = (const float*)d_in[6];
    const float* W2   = (const float*)d_in[7];
    const float* b2   = (const float*)d_in[8];
    int N = in_sizes[0];
    int E = in_sizes[1];
    float* out = (float*)d_out;

    int NBKT = (N + 255) >> 8;                    // buckets of 256 rows

    auto al = [](size_t x) { return (x + 255) & ~(size_t)255; };
    char* w = (char*)d_ws;
    int*      gcnt   = (int*)w;      w += al((size_t)NBKT * 4);
    int*      fstart = (int*)w;      w += al((size_t)(NBKT + 1) * 4);
    int*      gcur   = (int*)w;      w += al((size_t)NBKT * 4);
    int*      rs     = (int*)w;      w += al((size_t)(N + 1) * 4);
    uint2*    cv1    = (uint2*)w;    w += al((size_t)E * 8);
    uint2*    cv2    = (uint2*)w;    w += al((size_t)E * 8);
    unsigned* xw     = (unsigned*)w; w += al((size_t)N * 64 * 4);   // bf16 x

    float* agg = out;   // d_out doubles as agg scratch (dead until final dense)

    hipMemsetAsync(gcnt, 0, (size_t)NBKT * 4, stream);

    // x0 (bf16)
    gather_x0bf_k<<<(N * 64 + 255) / 256, 256, 0, stream>>>(nid, emb, xw, N);

    // CSR build: bucket-group then per-bucket row sort
    size_t ghistLds = (size_t)NBKT * 4;
    ghist_k<<<1024, 256, ghistLds, stream>>>(erow, gcnt, E, NBKT);
    scanB_k<<<1, 256, 0, stream>>>(gcnt, fstart, gcur, NBKT);
    size_t binLds = (size_t)BIN_TILE * 12 + (size_t)NBKT * 4 * 4;
    int binBlocks = (E + BIN_TILE - 1) / BIN_TILE;
    bin_k<<<binBlocks, BIN_THREADS, binLds, stream>>>(erow, ecol, eval, gcur, cv1, E, NBKT);
    rowsort_k<<<NBKT, 256, 0, stream>>>(fstart, cv1, cv2, rs, N, E);

    // layer 1: agg = A @ x0 ; x1(bf16) = relu(agg@W1+b1)
    spmm_k<<<(N * 64 + 255) / 256, 256, 0, stream>>>(rs, cv2, xw, agg, N);
    dense_k<<<2048, 256, 0, stream>>>(agg, W1, b1, nullptr, (unsigned short*)xw, N);

    // layer 2: agg = A @ x1 ; out(f32) = relu(agg@W2+b2)
    spmm_k<<<(N * 64 + 255) / 256, 256, 0, stream>>>(rs, cv2, xw, agg, N);
    dense_k<<<2048, 256, 0, stream>>>(agg, W2, b2, out, nullptr, N);
}